// Round 1
// 921.939 us; speedup vs baseline: 1.0230x; 1.0230x over previous
//
#include <hip/hip_runtime.h>

// Temporal GraphSAGE, P=4 periods, C=128, L=2 (reference constants).
// R6: (1) weight panel staged in LDS (64 KB) once per block -> kills the
// serialized L2-latency B loads (VGPR=80 forced load->wait->MFMA); all 16
// A fragments prefetched to VGPRs before the MFMA loop (launch_bounds(256,2)).
// (2) per-period compaction to involved nodes only (-44% row work):
// gemm/agg iterate compact node lists; agg buffer is compact-indexed.

#define CD 128

typedef __attribute__((ext_vector_type(8))) short s16x8;
typedef __attribute__((ext_vector_type(4))) float f32x4;

static __device__ __forceinline__ unsigned short f2bf(float f) {
  unsigned u = __float_as_uint(f);
  u += 0x7FFF + ((u >> 16) & 1);   // round-to-nearest-even
  return (unsigned short)(u >> 16);
}
static __device__ __forceinline__ float bf2f(unsigned us) {
  return __uint_as_float(us << 16);
}

// ---- histogram: per-(period,dst) degree + involved bitmask ----
__global__ __launch_bounds__(256) void histk(const int* __restrict__ ntime,
    const int* __restrict__ eidx, int* __restrict__ deg_pd, int* __restrict__ involved,
    const int* __restrict__ minp, const int* __restrict__ up, int N, int E) {
  int e = blockIdx.x * 256 + threadIdx.x;
  if (e >= E) return;
  int s = eidx[e], d = eidx[E + e];
  int ts = ntime[s], td = ntime[d];
  int m = ts > td ? ts : td;
  int p = (m - minp[0]) / up[0];
  atomicAdd(&deg_pd[p * N + d], 1);
  atomicOr(&involved[s], 1 << p);
  atomicOr(&involved[d], 1 << p);
}

// ---- per-period compaction of involved nodes ----
__global__ __launch_bounds__(256) void compk(const int* __restrict__ involved,
    int* __restrict__ nlist, int* __restrict__ ncnt, int N) {
  int i = blockIdx.x * 256 + threadIdx.x;
  if (i >= N) return;
  int bits = involved[i];
  if (!bits) return;
#pragma unroll
  for (int p = 0; p < 4; ++p)
    if ((bits >> p) & 1) {
      int pos = atomicAdd(&ncnt[p], 1);
      nlist[p * N + pos] = i;
    }
}

// ---- exclusive scan (3-phase) ----
__global__ __launch_bounds__(256) void scan1(const int* __restrict__ in,
    int* __restrict__ out, int* __restrict__ bsums, int M) {
  __shared__ int lds[256];
  int tid = threadIdx.x;
  int base = blockIdx.x * 1024 + tid * 4;
  int v0 = base + 0 < M ? in[base + 0] : 0;
  int v1 = base + 1 < M ? in[base + 1] : 0;
  int v2 = base + 2 < M ? in[base + 2] : 0;
  int v3 = base + 3 < M ? in[base + 3] : 0;
  int s = v0 + v1 + v2 + v3;
  lds[tid] = s;
  __syncthreads();
  for (int off = 1; off < 256; off <<= 1) {
    int t = tid >= off ? lds[tid - off] : 0;
    __syncthreads();
    lds[tid] += t;
    __syncthreads();
  }
  int run = lds[tid] - s;
  if (base + 0 < M) out[base + 0] = run; run += v0;
  if (base + 1 < M) out[base + 1] = run; run += v1;
  if (base + 2 < M) out[base + 2] = run; run += v2;
  if (base + 3 < M) out[base + 3] = run;
  if (tid == 255) bsums[blockIdx.x] = lds[255];
}

__global__ __launch_bounds__(256) void scan2(int* __restrict__ b, int M) {
  __shared__ int lds[256];
  int tid = threadIdx.x;
  int base = tid * 4;
  int v0 = base + 0 < M ? b[base + 0] : 0;
  int v1 = base + 1 < M ? b[base + 1] : 0;
  int v2 = base + 2 < M ? b[base + 2] : 0;
  int v3 = base + 3 < M ? b[base + 3] : 0;
  int s = v0 + v1 + v2 + v3;
  lds[tid] = s;
  __syncthreads();
  for (int off = 1; off < 256; off <<= 1) {
    int t = tid >= off ? lds[tid - off] : 0;
    __syncthreads();
    lds[tid] += t;
    __syncthreads();
  }
  int run = lds[tid] - s;
  if (base + 0 < M) b[base + 0] = run; run += v0;
  if (base + 1 < M) b[base + 1] = run; run += v1;
  if (base + 2 < M) b[base + 2] = run; run += v2;
  if (base + 3 < M) b[base + 3] = run;
}

__global__ __launch_bounds__(256) void scan3(int* __restrict__ out,
    const int* __restrict__ bsums, int M) {
  int add = bsums[blockIdx.x];
  int idx = blockIdx.x * 1024 + threadIdx.x;
#pragma unroll
  for (int k = 0; k < 4; ++k) {
    int i = idx + k * 256;
    if (i < M) out[i] += add;
  }
}

// ---- fill CSR col array; row_ptr doubles as cursor ----
__global__ __launch_bounds__(256) void fillk(const int* __restrict__ ntime,
    const int* __restrict__ eidx, int* __restrict__ row_ptr, int* __restrict__ col,
    const int* __restrict__ minp, const int* __restrict__ up, int N, int E) {
  int e = blockIdx.x * 256 + threadIdx.x;
  if (e >= E) return;
  int s = eidx[e], d = eidx[E + e];
  int ts = ntime[s], td = ntime[d];
  int m = ts > td ? ts : td;
  int p = (m - minp[0]) / up[0];
  int pos = atomicAdd(&row_ptr[p * N + d], 1);
  col[pos] = s;
}

// ---- weights: transpose + bf16, fragment-linear layout ----
// wt[l][q][n][j]: q in [0,32) = 16B k-block over K=256, n = output col,
// content k = q*8+j; k<128 from w_root[l][k][n], else w_nbr[l][k-128][n].
__global__ __launch_bounds__(256) void wprep(const float* __restrict__ wroot,
    const float* __restrict__ wnbr, unsigned short* __restrict__ wt, int total) {
  int t = blockIdx.x * 256 + threadIdx.x;
  if (t >= total) return;
  int l = t >> 12;
  int rem = t & 4095;
  int q = rem >> 7;
  int n = rem & 127;
  const float* w0 = wroot + l * CD * CD;
  const float* w1 = wnbr + l * CD * CD;
  unsigned short o[8];
#pragma unroll
  for (int j = 0; j < 8; ++j) {
    int k = q * 8 + j;
    float v = (k < CD) ? w0[k * CD + n] : w1[(k - CD) * CD + n];
    o[j] = f2bf(v);
  }
  uint4 pk;
  pk.x = (unsigned)o[0] | ((unsigned)o[1] << 16);
  pk.y = (unsigned)o[2] | ((unsigned)o[3] << 16);
  pk.z = (unsigned)o[4] | ((unsigned)o[5] << 16);
  pk.w = (unsigned)o[6] | ((unsigned)o[7] << 16);
  *(uint4*)(wt + (size_t)l * 32768 + ((size_t)q * CD + n) * 8) = pk;
}

// ---- x_bf init (+ fp32 mirror of seed rows for the head) ----
__global__ __launch_bounds__(256) void xprep(const float* __restrict__ x,
    float* __restrict__ x32, unsigned short* __restrict__ xb, int nseed, int total4) {
  int t = blockIdx.x * 256 + threadIdx.x;
  if (t >= total4) return;
  size_t i = (size_t)t * 4;
  float4 v = *(const float4*)(x + i);
  uint2 pk;
  pk.x = (unsigned)f2bf(v.x) | ((unsigned)f2bf(v.y) << 16);
  pk.y = (unsigned)f2bf(v.z) | ((unsigned)f2bf(v.w) << 16);
  *(uint2*)(xb + i) = pk;
  if ((int)(i >> 7) < nseed) *(float4*)(x32 + i) = v;
}

// ---- pull aggregation over compact involved list ----
// 16-lane group per compact index gi (dst node = nlp[gi]); agg stored at gi.
__global__ __launch_bounds__(256) void aggk(const unsigned short* __restrict__ hbf,
    unsigned short* __restrict__ aggbf, const int* __restrict__ row_ptr,
    const int* __restrict__ deg_pd, const int* __restrict__ col,
    const int* __restrict__ nlp, const int* __restrict__ pcnt, int p, int N) {
  int cnt = pcnt[0];
  int gi = blockIdx.x * 16 + (threadIdx.x >> 4);
  if (gi >= cnt) return;
  int d = nlp[gi];
  int lane = threadIdx.x & 15;
  int key = p * N + d;
  int dg = deg_pd[key];
  uint4 outv = make_uint4(0u, 0u, 0u, 0u);
  if (dg > 0) {
    int start = row_ptr[key] - dg;
    float a[8];
#pragma unroll
    for (int i = 0; i < 8; ++i) a[i] = 0.f;
    for (int j = 0; j < dg; ++j) {
      int s = col[start + j];
      uint4 r = *(const uint4*)(hbf + (size_t)s * CD + lane * 8);
      a[0] += bf2f(r.x & 0xffffu); a[1] += bf2f(r.x >> 16);
      a[2] += bf2f(r.y & 0xffffu); a[3] += bf2f(r.y >> 16);
      a[4] += bf2f(r.z & 0xffffu); a[5] += bf2f(r.z >> 16);
      a[6] += bf2f(r.w & 0xffffu); a[7] += bf2f(r.w >> 16);
    }
    float sc = 1.0f / (float)dg;
    outv.x = (unsigned)f2bf(a[0] * sc) | ((unsigned)f2bf(a[1] * sc) << 16);
    outv.y = (unsigned)f2bf(a[2] * sc) | ((unsigned)f2bf(a[3] * sc) << 16);
    outv.z = (unsigned)f2bf(a[4] * sc) | ((unsigned)f2bf(a[5] * sc) << 16);
    outv.w = (unsigned)f2bf(a[6] * sc) | ((unsigned)f2bf(a[7] * sc) << 16);
  }
  *(uint4*)(aggbf + (size_t)gi * CD + lane * 8) = outv;
}

// ---- MFMA GEMM + bias + LN (+relu -> h_bf | +residual -> x_bf [& x32 seeds]) ----
// Rows = compact involved list. B (128 cols x K=256 bf16 = 64 KB) staged in
// LDS once per block; K-loop is barrier-free. All 16 A fragments (wave-
// private 16B global loads) prefetched before the MFMA loop.
__global__ __launch_bounds__(256, 2) void gemm_mfma(
    const unsigned short* __restrict__ A1, const unsigned short* __restrict__ A2,
    const unsigned short* __restrict__ wt,
    const float* __restrict__ bias, const float* __restrict__ lng,
    const float* __restrict__ lnb,
    unsigned short* __restrict__ hout,
    float* __restrict__ x32, unsigned short* __restrict__ xbf,
    const int* __restrict__ nlp, const int* __restrict__ pcnt,
    int mode, int nseed) {
  int cnt = pcnt[0];
  int rbase = blockIdx.x * 128;
  if (rbase >= cnt) return;

  __shared__ unsigned short Blds[32768];   // 64 KB: whole layer weight panel
  {
    const uint4* src = (const uint4*)wt;
    uint4* dst = (uint4*)Blds;
#pragma unroll
    for (int i = 0; i < 16; ++i) dst[threadIdx.x + i * 256] = src[threadIdx.x + i * 256];
  }
  __syncthreads();

  int tid = threadIdx.x;
  int w = tid >> 6;
  int lane = tid & 63;
  int l15 = lane & 15;
  int quad = lane >> 4;

  // per-lane A rows via compact list (clamped; dup work discarded in epilogue)
  int idxA[2], nodeA[2];
#pragma unroll
  for (int rt = 0; rt < 2; ++rt) {
    int ii = rbase + w * 32 + rt * 16 + l15;
    ii = ii < cnt ? ii : cnt - 1;
    idxA[rt] = ii;
    nodeA[rt] = nlp[ii];
  }

  // prefetch ALL A fragments (16 x 16B = 64 VGPRs) up front
  s16x8 af[4][2][2];
#pragma unroll
  for (int kc = 0; kc < 4; ++kc) {
    int koff = (kc & 1) * 64;
#pragma unroll
    for (int ks = 0; ks < 2; ++ks) {
      int kb = (ks * 4 + quad) * 8;
#pragma unroll
      for (int rt = 0; rt < 2; ++rt) {
        const unsigned short* b = (kc < 2)
            ? A1 + (size_t)nodeA[rt] * CD
            : A2 + (size_t)idxA[rt] * CD;
        af[kc][ks][rt] = *(const s16x8*)(b + koff + kb);
      }
    }
  }

  f32x4 acc[2][8];
#pragma unroll
  for (int rt = 0; rt < 2; ++rt)
#pragma unroll
    for (int ct = 0; ct < 8; ++ct) acc[rt][ct] = (f32x4)(0.f);

#pragma unroll
  for (int kc = 0; kc < 4; ++kc) {
#pragma unroll
    for (int ks = 0; ks < 2; ++ks) {
      int q = kc * 8 + ks * 4 + quad;        // global 16B k-block in [0,32)
      s16x8 bfr[8];
#pragma unroll
      for (int ct = 0; ct < 8; ++ct)
        bfr[ct] = *(const s16x8*)&Blds[((size_t)q * CD + l15) * 8 + (size_t)ct * 128];
#pragma unroll
      for (int rt = 0; rt < 2; ++rt)
#pragma unroll
        for (int ct = 0; ct < 8; ++ct)
          acc[rt][ct] = __builtin_amdgcn_mfma_f32_16x16x32_bf16(
              af[kc][ks][rt], bfr[ct], acc[rt][ct], 0, 0, 0);
    }
  }

  // epilogue: bias + LayerNorm across the 16-lane row group
  float bb[8], gg[8], eb[8];
#pragma unroll
  for (int ct = 0; ct < 8; ++ct) {
    int c = ct * 16 + l15;
    bb[ct] = bias[c]; gg[ct] = lng[c]; eb[ct] = lnb[c];
  }
#pragma unroll
  for (int rt = 0; rt < 2; ++rt) {
#pragma unroll
    for (int reg = 0; reg < 4; ++reg) {
      int ridx = rbase + w * 32 + rt * 16 + quad * 4 + reg;
      float vals[8];
      float s = 0.f, ss = 0.f;
#pragma unroll
      for (int ct = 0; ct < 8; ++ct) {
        float v = acc[rt][ct][reg] + bb[ct];
        vals[ct] = v;
        s += v; ss += v * v;
      }
#pragma unroll
      for (int m = 1; m <= 8; m <<= 1) {
        s  += __shfl_xor(s, m, 64);
        ss += __shfl_xor(ss, m, 64);
      }
      float mu  = s * (1.0f / CD);
      float var = ss * (1.0f / CD) - mu * mu;
      float rs  = rsqrtf(var + 1e-5f);
      if (ridx < cnt) {
        int node = nlp[ridx];
        if (mode == 0) {
#pragma unroll
          for (int ct = 0; ct < 8; ++ct) {
            float o = (vals[ct] - mu) * rs * gg[ct] + eb[ct];
            o = fmaxf(o, 0.f);
            hout[(size_t)node * CD + ct * 16 + l15] = f2bf(o);
          }
        } else {
          bool seed = node < nseed;
#pragma unroll
          for (int ct = 0; ct < 8; ++ct) {
            float o = (vals[ct] - mu) * rs * gg[ct] + eb[ct];
            size_t idx = (size_t)node * CD + ct * 16 + l15;
            float xn = bf2f(xbf[idx]) + o;
            xbf[idx] = f2bf(xn);
            if (seed) x32[idx] += o;
          }
        }
      }
    }
  }
}

// ---- head (reads fp32 seed mirror) ----
__global__ __launch_bounds__(256) void headk(const float* __restrict__ x,
    const float* __restrict__ hw, const float* __restrict__ hb,
    float* __restrict__ out, int seeds) {
  int wave = threadIdx.x >> 6;
  int lane = threadIdx.x & 63;
  int row = blockIdx.x * 4 + wave;
  if (row >= seeds) return;
  const float* xp = x + (size_t)row * CD;
  float v = xp[lane] * hw[lane] + xp[64 + lane] * hw[64 + lane];
#pragma unroll
  for (int m = 1; m < 64; m <<= 1) v += __shfl_xor(v, m, 64);
  if (lane == 0) out[row] = v + hb[0];
}

extern "C" void kernel_launch(void* const* d_in, const int* in_sizes, int n_in,
                              void* d_out, int out_size, void* d_ws, size_t ws_size,
                              hipStream_t stream) {
  const float* x     = (const float*)d_in[0];
  const int*   ntime = (const int*)d_in[1];
  const int*   eidx  = (const int*)d_in[2];
  const float* wroot = (const float*)d_in[3];
  const float* wnbr  = (const float*)d_in[4];
  const float* bias  = (const float*)d_in[5];
  const float* lng   = (const float*)d_in[6];
  const float* lnb   = (const float*)d_in[7];
  const float* headw = (const float*)d_in[8];
  const float* headb = (const float*)d_in[9];
  const int*   minp  = (const int*)d_in[10];
  const int*   up    = (const int*)d_in[12];

  int N = in_sizes[0] / CD;
  int E = in_sizes[2] / 2;
  const int P = 4;
  int M = P * N;
  int nseed = out_size;   // OUT=1 per reference

  size_t off = 0;
  auto alloc = [&](size_t bytes) {
    void* p = (char*)d_ws + off;
    off += (bytes + 255) & ~(size_t)255;
    return p;
  };
  unsigned short* x_bf   = (unsigned short*)alloc((size_t)N * CD * 2);
  unsigned short* h_bf   = (unsigned short*)alloc((size_t)N * CD * 2);
  unsigned short* agg_bf = (unsigned short*)alloc((size_t)N * CD * 2);
  float*          x32    = (float*)alloc((size_t)nseed * CD * 4);
  unsigned short* wt     = (unsigned short*)alloc(2 * 32768 * 2);
  int* deg_pd   = (int*)alloc((size_t)M * 4);
  int* row_ptr  = (int*)alloc((size_t)M * 4);
  int* col      = (int*)alloc((size_t)E * 4);
  int* involved = (int*)alloc((size_t)N * 4);
  int* nlist    = (int*)alloc((size_t)M * 4);
  int* ncnt     = (int*)alloc(256);
  int* bsums    = (int*)alloc(4096);
  (void)ws_size;

  hipMemsetAsync(deg_pd, 0, (size_t)M * 4, stream);
  hipMemsetAsync(involved, 0, (size_t)N * 4, stream);
  hipMemsetAsync(ncnt, 0, 16, stream);

  int egrid = (E + 255) / 256;
  int NB = (M + 1023) / 1024;
  int ggrid = (N + 127) / 128;
  int agrid = (N + 15) / 16;

  xprep<<<(N * 32 + 255) / 256, 256, 0, stream>>>(x, x32, x_bf, nseed, N * 32);
  wprep<<<(8192 + 255) / 256, 256, 0, stream>>>(wroot, wnbr, wt, 8192);
  histk<<<egrid, 256, 0, stream>>>(ntime, eidx, deg_pd, involved, minp, up, N, E);
  compk<<<(N + 255) / 256, 256, 0, stream>>>(involved, nlist, ncnt, N);
  scan1<<<NB, 256, 0, stream>>>(deg_pd, row_ptr, bsums, M);
  scan2<<<1, 256, 0, stream>>>(bsums, NB);
  scan3<<<NB, 256, 0, stream>>>(row_ptr, bsums, M);
  fillk<<<egrid, 256, 0, stream>>>(ntime, eidx, row_ptr, col, minp, up, N, E);

  for (int p = 0; p < P; ++p) {
    const int* nlp = nlist + (size_t)p * N;
    const int* pc  = ncnt + p;
    aggk<<<agrid, 256, 0, stream>>>(x_bf, agg_bf, row_ptr, deg_pd, col, nlp, pc, p, N);
    gemm_mfma<<<ggrid, 256, 0, stream>>>(x_bf, agg_bf, wt,
        bias, lng, lnb, h_bf, nullptr, nullptr, nlp, pc, 0, nseed);
    aggk<<<agrid, 256, 0, stream>>>(h_bf, agg_bf, row_ptr, deg_pd, col, nlp, pc, p, N);
    gemm_mfma<<<ggrid, 256, 0, stream>>>(h_bf, agg_bf, wt + 32768,
        bias + CD, lng + CD, lnb + CD, nullptr, x32, x_bf, nlp, pc, 1, nseed);
  }
  headk<<<(nseed + 3) / 4, 256, 0, stream>>>(x32, headw, headb, (float*)d_out, nseed);
}